// Round 1
// baseline (3639.750 us; speedup 1.0000x reference)
//
#include <hip/hip_runtime.h>

// zhannRNN: x[8,512,512] -> xp GEMM -> 512-step tanh recurrence (HID=2048) -> out GEMM [*,128]
// Strategy:
//   Phase 1: xp[t][b][j] = x @ W_ih^T + b_ih + b_hh      (bf16 MFMA GEMM, M=4096,N=2048,K=512)
//   Phase 2: persistent scan kernel, 64 wgs, W_hh held in VGPRs as MFMA B-frags,
//            h exchanged via 32KB bf16 ping-pong in ws + hand-rolled device-scope grid barrier.
//   Phase 3: out = hs @ W_out^T + b_out                   (bf16 MFMA GEMM, M=4096,N=128,K=2048)

#define IN_K   512
#define HID    2048
#define OUTN   128
#define BB     8
#define TSTEPS 512
#define NWG    64   // scan workgroups; 32 j-rows each

typedef __bf16 bf16x8 __attribute__((ext_vector_type(8)));
typedef unsigned short u16x8 __attribute__((ext_vector_type(8)));
typedef float f32v4 __attribute__((ext_vector_type(4)));

union Frag8 { u16x8 u; bf16x8 b; };

__device__ __forceinline__ unsigned short f2bf(float f) {
  unsigned int u = __float_as_uint(f);
  return (unsigned short)((u + 0x7FFFu + ((u >> 16) & 1u)) >> 16);  // RNE
}

// ---------------- GEMM (phases 1 & 3) ----------------
// C[M x N] = A[M x K] * B[N x K]^T + bias. A fp32 (EPI0) or bf16/ushort (EPI1); B fp32.
// EPI0: writes Cout as xp[t][b][n] with bias0+bias1 (t = m&511, b = m>>9); also zeroes barrier.
// EPI1: writes Cout[m][n] + bias0[n].
template<int EPI>
__global__ __launch_bounds__(256, 2)
void gemm_kernel(const void* __restrict__ Aptr, const float* __restrict__ Bptr,
                 const float* __restrict__ bias0, const float* __restrict__ bias1,
                 float* __restrict__ Cout, const int Kdim, const int Ndim,
                 int* __restrict__ bar)
{
  if (EPI == 0 && blockIdx.x == 0 && blockIdx.y == 0 && threadIdx.x == 0) {
    bar[0] = 0;   // barrier arrival counter
    bar[32] = 0;  // barrier generation flag (separate cacheline)
  }
  // stride 56 ushorts = 112B: multiple of 16B (aligned ds_read_b128), bank step 28 -> <=2-way
  __shared__ __align__(16) unsigned short As[64][56];
  __shared__ __align__(16) unsigned short Bs[64][56];

  const int m0 = blockIdx.x * 64;
  const int n0 = blockIdx.y * 64;
  const int tid = threadIdx.x;
  const int w = tid >> 6, l = tid & 63;
  const int l15 = l & 15, lk = (l >> 4) * 8;
  const int wm = (w >> 1) * 32, wn = (w & 1) * 32;  // 2x2 wave grid, 32x32 per wave

  f32v4 acc[2][2];
  #pragma unroll
  for (int mt = 0; mt < 2; ++mt)
    #pragma unroll
    for (int nt = 0; nt < 2; ++nt)
      #pragma unroll
      for (int r = 0; r < 4; ++r) acc[mt][nt][r] = 0.0f;

  for (int k0 = 0; k0 < Kdim; k0 += 32) {
    __syncthreads();
    // stage A tile 64x32 -> bf16
    if (EPI == 0) {
      const float* A = (const float*)Aptr;
      const int r = tid >> 3, c4 = (tid & 7) * 4;
      #pragma unroll
      for (int it = 0; it < 2; ++it) {
        const float4 v = *(const float4*)(A + (size_t)(m0 + r + it * 32) * Kdim + k0 + c4);
        unsigned short* d = &As[r + it * 32][c4];
        d[0] = f2bf(v.x); d[1] = f2bf(v.y); d[2] = f2bf(v.z); d[3] = f2bf(v.w);
      }
    } else {
      const unsigned short* A = (const unsigned short*)Aptr;
      const int r = tid >> 2, c8 = (tid & 3) * 8;
      const u16x8 v = *(const u16x8*)(A + (size_t)(m0 + r) * Kdim + k0 + c8);
      *(u16x8*)&As[r][c8] = v;
    }
    // stage B tile 64x32 -> bf16 (B rows are output-n, K-contiguous)
    {
      const int r = tid >> 3, c4 = (tid & 7) * 4;
      #pragma unroll
      for (int it = 0; it < 2; ++it) {
        const float4 v = *(const float4*)(Bptr + (size_t)(n0 + r + it * 32) * Kdim + k0 + c4);
        unsigned short* d = &Bs[r + it * 32][c4];
        d[0] = f2bf(v.x); d[1] = f2bf(v.y); d[2] = f2bf(v.z); d[3] = f2bf(v.w);
      }
    }
    __syncthreads();

    Frag8 af[2], bg[2];
    #pragma unroll
    for (int mt = 0; mt < 2; ++mt) af[mt].u = *(const u16x8*)&As[wm + mt * 16 + l15][lk];
    #pragma unroll
    for (int nt = 0; nt < 2; ++nt) bg[nt].u = *(const u16x8*)&Bs[wn + nt * 16 + l15][lk];
    #pragma unroll
    for (int mt = 0; mt < 2; ++mt)
      #pragma unroll
      for (int nt = 0; nt < 2; ++nt)
        acc[mt][nt] = __builtin_amdgcn_mfma_f32_16x16x32_bf16(af[mt].b, bg[nt].b, acc[mt][nt], 0, 0, 0);
  }

  #pragma unroll
  for (int mt = 0; mt < 2; ++mt)
    #pragma unroll
    for (int nt = 0; nt < 2; ++nt)
      #pragma unroll
      for (int r = 0; r < 4; ++r) {
        const int m = m0 + wm + mt * 16 + (l >> 4) * 4 + r;   // C/D: row=(lane>>4)*4+reg
        const int n = n0 + wn + nt * 16 + l15;                // col = lane&15
        float v = acc[mt][nt][r];
        if (EPI == 0) {
          v += bias0[n] + bias1[n];
          const int b = m >> 9, t = m & 511;                  // x flat row = b*512 + t
          Cout[((size_t)t * BB + b) * Ndim + n] = v;          // xp[t][b][n]
        } else {
          v += bias0[n];
          Cout[(size_t)m * Ndim + n] = v;
        }
      }
}

// ---------------- Phase 2: persistent recurrence scan ----------------
__global__ __launch_bounds__(256, 1)
void scan_kernel(const float* __restrict__ Whh, const float* __restrict__ xp,
                 unsigned short* __restrict__ hbuf, unsigned short* __restrict__ hs,
                 int* __restrict__ bar)
{
  const int g = blockIdx.x;
  const int tid = threadIdx.x;
  const int w = tid >> 6, l = tid & 63;     // wave w owns K-chunk [w*512, w*512+512)
  const int l15 = l & 15, lk = (l >> 4) * 8;
  const int jbase = g * 32;                 // wg owns output neurons [jbase, jbase+32)

  // Preload W_hh slice as MFMA B-fragments into registers (128 VGPRs), bf16.
  // B[k][n] = W_hh[jbase+nt*16+(l&15)][k], k = w*512 + kc*32 + (l>>4)*8 + i
  Frag8 Bw[2][16];
  #pragma unroll
  for (int nt = 0; nt < 2; ++nt) {
    const int j = jbase + nt * 16 + l15;
    #pragma unroll
    for (int kc = 0; kc < 16; ++kc) {
      const int k = w * 512 + kc * 32 + lk;
      const float4* p = (const float4*)(Whh + (size_t)j * HID + k);
      const float4 u0 = p[0], u1 = p[1];
      Frag8 f;
      f.u[0] = f2bf(u0.x); f.u[1] = f2bf(u0.y); f.u[2] = f2bf(u0.z); f.u[3] = f2bf(u0.w);
      f.u[4] = f2bf(u1.x); f.u[5] = f2bf(u1.y); f.u[6] = f2bf(u1.z); f.u[7] = f2bf(u1.w);
      Bw[nt][kc] = f;
    }
  }

  __shared__ float red[4][2][16][16];  // per-wave partial C tiles, 8KB
  int* cnt = &bar[0];
  int* gen = &bar[32];
  int lgen = 0;
  const int om = tid >> 5, oj = tid & 31;  // epilogue: thread -> (batch om<8, j-offset oj)

  for (int t = 0; t < TSTEPS; ++t) {
    f32v4 acc0, acc1;
    #pragma unroll
    for (int r = 0; r < 4; ++r) { acc0[r] = 0.0f; acc1[r] = 0.0f; }

    if (t > 0) {  // h_{-1} == 0: skip matmul entirely at t==0
      const unsigned short* hb = hbuf + ((t & 1) ^ 1) * (BB * HID);
      #pragma unroll
      for (int kc = 0; kc < 16; ++kc) {
        Frag8 a;
        #pragma unroll
        for (int i = 0; i < 8; ++i) a.u[i] = 0;
        if (l15 < BB) {  // A rows 8..15 are zero padding
          const int k = w * 512 + kc * 32 + lk;
          a.u = *(const u16x8*)(hb + l15 * HID + k);
        }
        acc0 = __builtin_amdgcn_mfma_f32_16x16x32_bf16(a.b, Bw[0][kc].b, acc0, 0, 0, 0);
        acc1 = __builtin_amdgcn_mfma_f32_16x16x32_bf16(a.b, Bw[1][kc].b, acc1, 0, 0, 0);
      }
    }

    // cross-wave K-reduction via LDS
    #pragma unroll
    for (int r = 0; r < 4; ++r) {
      red[w][0][(l >> 4) * 4 + r][l15] = acc0[r];
      red[w][1][(l >> 4) * 4 + r][l15] = acc1[r];
    }
    __syncthreads();
    float s = red[0][oj >> 4][om][oj & 15] + red[1][oj >> 4][om][oj & 15]
            + red[2][oj >> 4][om][oj & 15] + red[3][oj >> 4][om][oj & 15];
    s += xp[((size_t)t * BB + om) * HID + jbase + oj];
    const float hv = tanhf(s);
    const unsigned short hb16 = f2bf(hv);
    hbuf[(t & 1) * (BB * HID) + om * HID + jbase + oj] = hb16;  // ping-pong write
    hs[((size_t)om * TSTEPS + t) * HID + jbase + oj] = hb16;    // hs[b][t][j] for phase 3

    // ---- device-scope grid barrier (64 co-resident wgs) ----
    __syncthreads();  // drains this wg's stores (vmcnt) before release
    if (tid == 0) {
      const int gv = lgen;
      const int prev = __hip_atomic_fetch_add(cnt, 1, __ATOMIC_ACQ_REL, __HIP_MEMORY_SCOPE_AGENT);
      if (prev == NWG - 1) {
        __hip_atomic_store(cnt, 0, __ATOMIC_RELAXED, __HIP_MEMORY_SCOPE_AGENT);
        __hip_atomic_store(gen, gv + 1, __ATOMIC_RELEASE, __HIP_MEMORY_SCOPE_AGENT);
      } else {
        while (__hip_atomic_load(gen, __ATOMIC_RELAXED, __HIP_MEMORY_SCOPE_AGENT) <= gv) {
          __builtin_amdgcn_s_sleep(1);
        }
        __builtin_amdgcn_fence(__ATOMIC_ACQUIRE, "agent");  // invalidate L1/L2 before h reads
      }
      lgen = gv + 1;
    }
    __syncthreads();
  }
}

extern "C" void kernel_launch(void* const* d_in, const int* in_sizes, int n_in,
                              void* d_out, int out_size, void* d_ws, size_t ws_size,
                              hipStream_t stream)
{
  (void)in_sizes; (void)n_in; (void)out_size; (void)ws_size;
  const float* x    = (const float*)d_in[0];
  const float* Wih  = (const float*)d_in[1];
  const float* bih  = (const float*)d_in[2];
  const float* Whh  = (const float*)d_in[3];
  const float* bhh  = (const float*)d_in[4];
  const float* Wout = (const float*)d_in[5];
  const float* bout = (const float*)d_in[6];
  float* out = (float*)d_out;

  char* ws = (char*)d_ws;
  float* xp            = (float*)(ws);                                   // [512][8][2048] fp32, 32 MiB
  unsigned short* hs   = (unsigned short*)(ws + (size_t)(32 << 20));     // [8][512][2048] bf16, 16 MiB
  unsigned short* hbuf = (unsigned short*)(ws + (size_t)(48 << 20));     // [2][8][2048] bf16, 64 KiB
  int* bar             = (int*)(ws + (size_t)(49 << 20));                // barrier state (reset by phase 1)

  // Phase 1: xp = x @ W_ih^T + b_ih + b_hh  (also zeroes barrier state for this launch)
  gemm_kernel<0><<<dim3(64, 32), 256, 0, stream>>>(x, Wih, bih, bhh, xp, IN_K, HID, bar);
  // Phase 2: sequential scan, 512 grid-barriered steps
  scan_kernel<<<dim3(NWG), 256, 0, stream>>>(Whh, xp, hbuf, hs, bar);
  // Phase 3: out = hs @ W_out^T + b_out
  gemm_kernel<1><<<dim3(64, 2), 256, 0, stream>>>(hs, Wout, bout, nullptr, out, HID, OUTN, bar);
}

// Round 2
// 2349.453 us; speedup vs baseline: 1.5492x; 1.5492x over previous
//
#include <hip/hip_runtime.h>

// zhannRNN: x[8,512,512] -> xp GEMM -> 512-step tanh recurrence (HID=2048) -> out GEMM [*,128]
//   Phase 1: xp[t][b][j] = x @ W_ih^T + b_ih + b_hh      (bf16 MFMA GEMM)
//   Phase 2: persistent scan, 64 wgs, W_hh in VGPRs; h exchange via cache-BYPASSING
//            (sc0 sc1) loads/stores through the memory-side L3 + fence-free monotonic
//            grid barrier (no buffer_wbl2 / buffer_inv on the critical path).
//   Phase 3: out = hs @ W_out^T + b_out                   (bf16 MFMA GEMM)

#define IN_K   512
#define HID    2048
#define OUTN   128
#define BB     8
#define TSTEPS 512
#define NWG    64

typedef __bf16 bf16x8 __attribute__((ext_vector_type(8)));
typedef unsigned short u16x8 __attribute__((ext_vector_type(8)));
typedef float f32v4 __attribute__((ext_vector_type(4)));

union Frag8 { u16x8 u; bf16x8 b; };

__device__ __forceinline__ unsigned short f2bf(float f) {
  unsigned int u = __float_as_uint(f);
  return (unsigned short)((u + 0x7FFFu + ((u >> 16) & 1u)) >> 16);  // RNE
}

__device__ __forceinline__ float tanh_fast(float x) {
  // 1 - 2/(e^{2x}+1); exact at +-inf, ~1e-6 abs err, far below bf16 rounding
  return 1.0f - 2.0f / (__expf(2.0f * x) + 1.0f);
}

// ---------------- GEMM (phases 1 & 3) ---------------- (unchanged from R0)
template<int EPI>
__global__ __launch_bounds__(256, 2)
void gemm_kernel(const void* __restrict__ Aptr, const float* __restrict__ Bptr,
                 const float* __restrict__ bias0, const float* __restrict__ bias1,
                 float* __restrict__ Cout, const int Kdim, const int Ndim,
                 int* __restrict__ bar)
{
  if (EPI == 0 && blockIdx.x == 0 && blockIdx.y == 0 && threadIdx.x == 0) {
    bar[0] = 0;   // barrier arrival counter (monotonic within one scan launch)
    bar[32] = 0;  // barrier generation flag (separate 128B line)
  }
  __shared__ __align__(16) unsigned short As[64][56];
  __shared__ __align__(16) unsigned short Bs[64][56];

  const int m0 = blockIdx.x * 64;
  const int n0 = blockIdx.y * 64;
  const int tid = threadIdx.x;
  const int w = tid >> 6, l = tid & 63;
  const int l15 = l & 15, lk = (l >> 4) * 8;
  const int wm = (w >> 1) * 32, wn = (w & 1) * 32;

  f32v4 acc[2][2];
  #pragma unroll
  for (int mt = 0; mt < 2; ++mt)
    #pragma unroll
    for (int nt = 0; nt < 2; ++nt)
      #pragma unroll
      for (int r = 0; r < 4; ++r) acc[mt][nt][r] = 0.0f;

  for (int k0 = 0; k0 < Kdim; k0 += 32) {
    __syncthreads();
    if (EPI == 0) {
      const float* A = (const float*)Aptr;
      const int r = tid >> 3, c4 = (tid & 7) * 4;
      #pragma unroll
      for (int it = 0; it < 2; ++it) {
        const float4 v = *(const float4*)(A + (size_t)(m0 + r + it * 32) * Kdim + k0 + c4);
        unsigned short* d = &As[r + it * 32][c4];
        d[0] = f2bf(v.x); d[1] = f2bf(v.y); d[2] = f2bf(v.z); d[3] = f2bf(v.w);
      }
    } else {
      const unsigned short* A = (const unsigned short*)Aptr;
      const int r = tid >> 2, c8 = (tid & 3) * 8;
      const u16x8 v = *(const u16x8*)(A + (size_t)(m0 + r) * Kdim + k0 + c8);
      *(u16x8*)&As[r][c8] = v;
    }
    {
      const int r = tid >> 3, c4 = (tid & 7) * 4;
      #pragma unroll
      for (int it = 0; it < 2; ++it) {
        const float4 v = *(const float4*)(Bptr + (size_t)(n0 + r + it * 32) * Kdim + k0 + c4);
        unsigned short* d = &Bs[r + it * 32][c4];
        d[0] = f2bf(v.x); d[1] = f2bf(v.y); d[2] = f2bf(v.z); d[3] = f2bf(v.w);
      }
    }
    __syncthreads();

    Frag8 af[2], bg[2];
    #pragma unroll
    for (int mt = 0; mt < 2; ++mt) af[mt].u = *(const u16x8*)&As[wm + mt * 16 + l15][lk];
    #pragma unroll
    for (int nt = 0; nt < 2; ++nt) bg[nt].u = *(const u16x8*)&Bs[wn + nt * 16 + l15][lk];
    #pragma unroll
    for (int mt = 0; mt < 2; ++mt)
      #pragma unroll
      for (int nt = 0; nt < 2; ++nt)
        acc[mt][nt] = __builtin_amdgcn_mfma_f32_16x16x32_bf16(af[mt].b, bg[nt].b, acc[mt][nt], 0, 0, 0);
  }

  #pragma unroll
  for (int mt = 0; mt < 2; ++mt)
    #pragma unroll
    for (int nt = 0; nt < 2; ++nt)
      #pragma unroll
      for (int r = 0; r < 4; ++r) {
        const int m = m0 + wm + mt * 16 + (l >> 4) * 4 + r;
        const int n = n0 + wn + nt * 16 + l15;
        float v = acc[mt][nt][r];
        if (EPI == 0) {
          v += bias0[n] + bias1[n];
          const int b = m >> 9, t = m & 511;
          Cout[((size_t)t * BB + b) * Ndim + n] = v;
        } else {
          v += bias0[n];
          Cout[(size_t)m * Ndim + n] = v;
        }
      }
}

// ---------------- Phase 2: persistent recurrence scan ----------------
__global__ __launch_bounds__(256, 1)
void scan_kernel(const float* __restrict__ Whh, const float* __restrict__ xp,
                 unsigned short* __restrict__ hbuf, unsigned short* __restrict__ hs,
                 int* __restrict__ bar)
{
  const int g = blockIdx.x;
  const int tid = threadIdx.x;
  const int w = tid >> 6, l = tid & 63;     // wave w owns K-chunk [w*512, w*512+512)
  const int l15 = l & 15, lk = (l >> 4) * 8;
  const int jbase = g * 32;                 // wg owns output neurons [jbase, jbase+32)

  // Preload W_hh slice as MFMA B-fragments (128 VGPRs), bf16.
  Frag8 Bw[2][16];
  #pragma unroll
  for (int nt = 0; nt < 2; ++nt) {
    const int j = jbase + nt * 16 + l15;
    #pragma unroll
    for (int kc = 0; kc < 16; ++kc) {
      const int k = w * 512 + kc * 32 + lk;
      const float4* p = (const float4*)(Whh + (size_t)j * HID + k);
      const float4 u0 = p[0], u1 = p[1];
      Frag8 f;
      f.u[0] = f2bf(u0.x); f.u[1] = f2bf(u0.y); f.u[2] = f2bf(u0.z); f.u[3] = f2bf(u0.w);
      f.u[4] = f2bf(u1.x); f.u[5] = f2bf(u1.y); f.u[6] = f2bf(u1.z); f.u[7] = f2bf(u1.w);
      Bw[nt][kc] = f;
    }
  }

  __shared__ float red[4][2][16][16];  // per-wave partial C tiles, 8KB
  int* cnt = &bar[0];
  int* gen = &bar[32];

  const int om = tid >> 4;             // (valid for tid<128) batch index
  const int oj2 = (tid & 15) * 2;      // even j offset; thread handles oj2, oj2+1
  const int half = oj2 >> 4, col = oj2 & 15;
  const int arow = l15 & 7;            // A-frag row; rows 8..15 duplicate 0..7 (C rows 8..15 unused)

  for (int t = 0; t < TSTEPS; ++t) {
    // xp load (independent of h) — issue early, overlaps with h loads
    float xv0 = 0.f, xv1 = 0.f;
    if (tid < 128) {
      const float2 xv = *(const float2*)(xp + ((size_t)t * BB + om) * HID + jbase + oj2);
      xv0 = xv.x; xv1 = xv.y;
    }

    f32v4 acc0, acc1;
    #pragma unroll
    for (int r = 0; r < 4; ++r) { acc0[r] = 0.f; acc1[r] = 0.f; }

    if (t > 0) {  // h_{-1} == 0: skip matmul at t==0
      const unsigned short* hb = hbuf + ((t & 1) ^ 1) * (BB * HID)
                               + (size_t)arow * HID + w * 512 + lk;
      Frag8 a[16];
      #pragma unroll
      for (int kc = 0; kc < 16; ++kc) {
        // cache-bypassing 16B load: reads coherence point (L3), no stale L1/L2
        asm volatile("global_load_dwordx4 %0, %1, off offset:%2 sc0 sc1"
                     : "=v"(a[kc].u) : "v"(hb), "n"(kc * 64));
      }
      asm volatile("s_waitcnt vmcnt(0)" ::: "memory");
      __builtin_amdgcn_sched_barrier(0);  // rule #18: pin MFMAs after the waitcnt
      #pragma unroll
      for (int kc = 0; kc < 16; ++kc) {
        acc0 = __builtin_amdgcn_mfma_f32_16x16x32_bf16(a[kc].b, Bw[0][kc].b, acc0, 0, 0, 0);
        acc1 = __builtin_amdgcn_mfma_f32_16x16x32_bf16(a[kc].b, Bw[1][kc].b, acc1, 0, 0, 0);
      }
    }

    // cross-wave K-reduction via LDS
    #pragma unroll
    for (int r = 0; r < 4; ++r) {
      red[w][0][(l >> 4) * 4 + r][l15] = acc0[r];
      red[w][1][(l >> 4) * 4 + r][l15] = acc1[r];
    }
    __syncthreads();

    if (tid < 128) {
      float s0 = red[0][half][om][col]     + red[1][half][om][col]
               + red[2][half][om][col]     + red[3][half][om][col]     + xv0;
      float s1 = red[0][half][om][col + 1] + red[1][half][om][col + 1]
               + red[2][half][om][col + 1] + red[3][half][om][col + 1] + xv1;
      const float h0 = tanh_fast(s0), h1 = tanh_fast(s1);
      const unsigned int packed = (unsigned int)f2bf(h0) | ((unsigned int)f2bf(h1) << 16);
      // exchange value: agent-scope write-through store -> lands at coherence point
      unsigned int* hp = (unsigned int*)(hbuf + (t & 1) * (BB * HID) + (size_t)om * HID + jbase + oj2);
      __hip_atomic_store(hp, packed, __ATOMIC_RELAXED, __HIP_MEMORY_SCOPE_AGENT);
      // hs: normal cached store (consumed by phase 3 after end-of-kernel flush)
      *(unsigned int*)(hs + ((size_t)om * TSTEPS + t) * HID + jbase + oj2) = packed;
    }

    // ---- fence-free monotonic grid barrier ----
    asm volatile("s_waitcnt vmcnt(0)" ::: "memory");  // h stores performed (at L3) before arrival
    __syncthreads();
    if (tid == 0) {
      const int prev = __hip_atomic_fetch_add(cnt, 1, __ATOMIC_RELAXED, __HIP_MEMORY_SCOPE_AGENT);
      if ((prev & (NWG - 1)) == NWG - 1) {
        // last arriver: RMW total order => all 63 others' h stores already visible
        __hip_atomic_store(gen, t + 1, __ATOMIC_RELAXED, __HIP_MEMORY_SCOPE_AGENT);
      } else {
        while (__hip_atomic_load(gen, __ATOMIC_RELAXED, __HIP_MEMORY_SCOPE_AGENT) <= t) {}
      }
    }
    __syncthreads();
  }
}

extern "C" void kernel_launch(void* const* d_in, const int* in_sizes, int n_in,
                              void* d_out, int out_size, void* d_ws, size_t ws_size,
                              hipStream_t stream)
{
  (void)in_sizes; (void)n_in; (void)out_size; (void)ws_size;
  const float* x    = (const float*)d_in[0];
  const float* Wih  = (const float*)d_in[1];
  const float* bih  = (const float*)d_in[2];
  const float* Whh  = (const float*)d_in[3];
  const float* bhh  = (const float*)d_in[4];
  const float* Wout = (const float*)d_in[5];
  const float* bout = (const float*)d_in[6];
  float* out = (float*)d_out;

  char* ws = (char*)d_ws;
  float* xp            = (float*)(ws);                                   // [512][8][2048] fp32, 32 MiB
  unsigned short* hs   = (unsigned short*)(ws + (size_t)(32 << 20));     // [8][512][2048] bf16, 16 MiB
  unsigned short* hbuf = (unsigned short*)(ws + (size_t)(48 << 20));     // [2][8][2048] bf16, 64 KiB
  int* bar             = (int*)(ws + (size_t)(49 << 20));                // barrier state (reset by phase 1)

  gemm_kernel<0><<<dim3(64, 32), 256, 0, stream>>>(x, Wih, bih, bhh, xp, IN_K, HID, bar);
  scan_kernel<<<dim3(NWG), 256, 0, stream>>>(Whh, xp, hbuf, hs, bar);
  gemm_kernel<1><<<dim3(64, 2), 256, 0, stream>>>(hs, Wout, bout, nullptr, out, HID, OUTN, bar);
}

// Round 3
// 1987.116 us; speedup vs baseline: 1.8317x; 1.1823x over previous
//
#include <hip/hip_runtime.h>

// zhannRNN: x[8,512,512] -> xp GEMM -> 512-step tanh recurrence (HID=2048) -> out GEMM [*,128]
//   Phase 0: fill hs with sentinel 0xFF80FF80 (-Inf bf16 pairs; impossible as tanh output)
//   Phase 1: xp[t][b][j] = x @ W_ih^T + b_ih + b_hh      (bf16 MFMA GEMM)
//   Phase 2: persistent scan, 64 wgs, W_hh in VGPRs. NO grid barrier: h_t lands in the
//            unique slice hs[b][t][j]; consumers poll the DATA through L3 (sc0 sc1) and
//            detect readiness via the sentinel. Store itself is the ready signal.
//   Phase 3: out = hs @ W_out^T + b_out                   (bf16 MFMA GEMM)

#define IN_K   512
#define HID    2048
#define OUTN   128
#define BB     8
#define TSTEPS 512
#define NWG    64
#define SENT   0xFF80FF80u

typedef __bf16 bf16x8 __attribute__((ext_vector_type(8)));
typedef unsigned short u16x8 __attribute__((ext_vector_type(8)));
typedef unsigned int u32x4 __attribute__((ext_vector_type(4)));
typedef float f32v4 __attribute__((ext_vector_type(4)));

union Frag8 { u16x8 u; bf16x8 b; u32x4 d; };

__device__ __forceinline__ unsigned short f2bf(float f) {
  unsigned int u = __float_as_uint(f);
  return (unsigned short)((u + 0x7FFFu + ((u >> 16) & 1u)) >> 16);  // RNE
}

__device__ __forceinline__ float tanh_fast(float x) {
  return 1.0f - 2.0f / (__expf(2.0f * x) + 1.0f);  // ~1e-6 abs err, << bf16 rounding
}

// ---------------- Phase 0: sentinel fill ----------------
__global__ __launch_bounds__(256)
void sentinel_kernel(u32x4* __restrict__ p) {
  const size_t i = (size_t)blockIdx.x * 256 + threadIdx.x;
  u32x4 v; v[0] = SENT; v[1] = SENT; v[2] = SENT; v[3] = SENT;
  p[i] = v;
}

// ---------------- GEMM (phases 1 & 3) ----------------
template<int EPI>
__global__ __launch_bounds__(256, 2)
void gemm_kernel(const void* __restrict__ Aptr, const float* __restrict__ Bptr,
                 const float* __restrict__ bias0, const float* __restrict__ bias1,
                 float* __restrict__ Cout, const int Kdim, const int Ndim)
{
  __shared__ __align__(16) unsigned short As[64][56];
  __shared__ __align__(16) unsigned short Bs[64][56];

  const int m0 = blockIdx.x * 64;
  const int n0 = blockIdx.y * 64;
  const int tid = threadIdx.x;
  const int w = tid >> 6, l = tid & 63;
  const int l15 = l & 15, lk = (l >> 4) * 8;
  const int wm = (w >> 1) * 32, wn = (w & 1) * 32;

  f32v4 acc[2][2];
  #pragma unroll
  for (int mt = 0; mt < 2; ++mt)
    #pragma unroll
    for (int nt = 0; nt < 2; ++nt)
      #pragma unroll
      for (int r = 0; r < 4; ++r) acc[mt][nt][r] = 0.0f;

  for (int k0 = 0; k0 < Kdim; k0 += 32) {
    __syncthreads();
    if (EPI == 0) {
      const float* A = (const float*)Aptr;
      const int r = tid >> 3, c4 = (tid & 7) * 4;
      #pragma unroll
      for (int it = 0; it < 2; ++it) {
        const float4 v = *(const float4*)(A + (size_t)(m0 + r + it * 32) * Kdim + k0 + c4);
        unsigned short* d = &As[r + it * 32][c4];
        d[0] = f2bf(v.x); d[1] = f2bf(v.y); d[2] = f2bf(v.z); d[3] = f2bf(v.w);
      }
    } else {
      const unsigned short* A = (const unsigned short*)Aptr;
      const int r = tid >> 2, c8 = (tid & 3) * 8;
      const u16x8 v = *(const u16x8*)(A + (size_t)(m0 + r) * Kdim + k0 + c8);
      *(u16x8*)&As[r][c8] = v;
    }
    {
      const int r = tid >> 3, c4 = (tid & 7) * 4;
      #pragma unroll
      for (int it = 0; it < 2; ++it) {
        const float4 v = *(const float4*)(Bptr + (size_t)(n0 + r + it * 32) * Kdim + k0 + c4);
        unsigned short* d = &Bs[r + it * 32][c4];
        d[0] = f2bf(v.x); d[1] = f2bf(v.y); d[2] = f2bf(v.z); d[3] = f2bf(v.w);
      }
    }
    __syncthreads();

    Frag8 af[2], bg[2];
    #pragma unroll
    for (int mt = 0; mt < 2; ++mt) af[mt].u = *(const u16x8*)&As[wm + mt * 16 + l15][lk];
    #pragma unroll
    for (int nt = 0; nt < 2; ++nt) bg[nt].u = *(const u16x8*)&Bs[wn + nt * 16 + l15][lk];
    #pragma unroll
    for (int mt = 0; mt < 2; ++mt)
      #pragma unroll
      for (int nt = 0; nt < 2; ++nt)
        acc[mt][nt] = __builtin_amdgcn_mfma_f32_16x16x32_bf16(af[mt].b, bg[nt].b, acc[mt][nt], 0, 0, 0);
  }

  #pragma unroll
  for (int mt = 0; mt < 2; ++mt)
    #pragma unroll
    for (int nt = 0; nt < 2; ++nt)
      #pragma unroll
      for (int r = 0; r < 4; ++r) {
        const int m = m0 + wm + mt * 16 + (l >> 4) * 4 + r;
        const int n = n0 + wn + nt * 16 + l15;
        float v = acc[mt][nt][r];
        if (EPI == 0) {
          v += bias0[n] + bias1[n];
          const int b = m >> 9, t = m & 511;
          Cout[((size_t)t * BB + b) * Ndim + n] = v;
        } else {
          v += bias0[n];
          Cout[(size_t)m * Ndim + n] = v;
        }
      }
}

// ---------------- Phase 2: barrier-free sentinel-dataflow scan ----------------
__global__ __launch_bounds__(256, 1)
void scan_kernel(const float* __restrict__ Whh, const float* __restrict__ xp,
                 unsigned short* __restrict__ hs)
{
  const int g = blockIdx.x;
  const int tid = threadIdx.x;
  const int w = tid >> 6, l = tid & 63;     // wave w owns K-chunk [w*512, w*512+512)
  const int l15 = l & 15, lk = (l >> 4) * 8;
  const int jbase = g * 32;                 // wg owns output neurons [jbase, jbase+32)

  // Preload W_hh slice as MFMA B-fragments (128 VGPRs), bf16.
  Frag8 Bw[2][16];
  #pragma unroll
  for (int nt = 0; nt < 2; ++nt) {
    const int j = jbase + nt * 16 + l15;
    #pragma unroll
    for (int kc = 0; kc < 16; ++kc) {
      const int k = w * 512 + kc * 32 + lk;
      const float4* p = (const float4*)(Whh + (size_t)j * HID + k);
      const float4 u0 = p[0], u1 = p[1];
      Frag8 f;
      f.u[0] = f2bf(u0.x); f.u[1] = f2bf(u0.y); f.u[2] = f2bf(u0.z); f.u[3] = f2bf(u0.w);
      f.u[4] = f2bf(u1.x); f.u[5] = f2bf(u1.y); f.u[6] = f2bf(u1.z); f.u[7] = f2bf(u1.w);
      Bw[nt][kc] = f;
    }
  }

  __shared__ float red[4][2][16][16];  // per-wave partial C tiles, 8KB
  const int om = tid >> 4;             // (tid<128) batch index
  const int oj2 = (tid & 15) * 2;      // thread handles j-offsets oj2, oj2+1
  const int half = oj2 >> 4, col = oj2 & 15;
  const int arow = l15 & 7;            // A rows 8..15 duplicate 0..7 (same addr -> coalesced)

  for (int t = 0; t < TSTEPS; ++t) {
    // xp load (independent of h) — overlaps the poll
    float xv0 = 0.f, xv1 = 0.f;
    if (tid < 128) {
      const float2 xv = *(const float2*)(xp + ((size_t)t * BB + om) * HID + jbase + oj2);
      xv0 = xv.x; xv1 = xv.y;
    }

    f32v4 acc0, acc1;
    #pragma unroll
    for (int r = 0; r < 4; ++r) { acc0[r] = 0.f; acc1[r] = 0.f; }

    if (t > 0) {  // h_{-1} == 0
      // consumer reads h_{t-1} from hs[b][t-1][kchunk]; poll data through L3 until no sentinel
      const unsigned short* hb = hs + ((size_t)arow * TSTEPS + (t - 1)) * HID + w * 512 + lk;
      Frag8 a[16];
      while (true) {
        #pragma unroll
        for (int kc = 0; kc < 16; ++kc) {
          asm volatile("global_load_dwordx4 %0, %1, off offset:%2 sc0 sc1"
                       : "=v"(a[kc].d) : "v"(hb), "n"(kc * 64));
        }
        asm volatile("s_waitcnt vmcnt(0)" ::: "memory");
        unsigned int mv = 0xFFFFFFFFu;
        #pragma unroll
        for (int kc = 0; kc < 16; ++kc)
          #pragma unroll
          for (int dwi = 0; dwi < 4; ++dwi)
            mv = min(mv, a[kc].d[dwi] ^ SENT);  // ==0 iff that dword is still sentinel
        if (__all(mv != 0u)) break;
      }
      __builtin_amdgcn_sched_barrier(0);  // rule #18: MFMAs stay after the waitcnt/poll
      #pragma unroll
      for (int kc = 0; kc < 16; ++kc) {
        acc0 = __builtin_amdgcn_mfma_f32_16x16x32_bf16(a[kc].b, Bw[0][kc].b, acc0, 0, 0, 0);
        acc1 = __builtin_amdgcn_mfma_f32_16x16x32_bf16(a[kc].b, Bw[1][kc].b, acc1, 0, 0, 0);
      }
    }

    // cross-wave K-reduction via LDS
    #pragma unroll
    for (int r = 0; r < 4; ++r) {
      red[w][0][(l >> 4) * 4 + r][l15] = acc0[r];
      red[w][1][(l >> 4) * 4 + r][l15] = acc1[r];
    }
    __syncthreads();

    if (tid < 128) {
      float s0 = red[0][half][om][col]     + red[1][half][om][col]
               + red[2][half][om][col]     + red[3][half][om][col]     + xv0;
      float s1 = red[0][half][om][col + 1] + red[1][half][om][col + 1]
               + red[2][half][om][col + 1] + red[3][half][om][col + 1] + xv1;
      const float h0 = tanh_fast(s0), h1 = tanh_fast(s1);
      const unsigned int packed = (unsigned int)f2bf(h0) | ((unsigned int)f2bf(h1) << 16);
      // THE signal: write-through agent store into the unique per-step slice of hs
      unsigned int* hp = (unsigned int*)(hs + ((size_t)om * TSTEPS + t) * HID + jbase + oj2);
      __hip_atomic_store(hp, packed, __ATOMIC_RELAXED, __HIP_MEMORY_SCOPE_AGENT);
    }
    __syncthreads();  // red[] reuse discipline for next step
  }
}

extern "C" void kernel_launch(void* const* d_in, const int* in_sizes, int n_in,
                              void* d_out, int out_size, void* d_ws, size_t ws_size,
                              hipStream_t stream)
{
  (void)in_sizes; (void)n_in; (void)out_size; (void)ws_size;
  const float* x    = (const float*)d_in[0];
  const float* Wih  = (const float*)d_in[1];
  const float* bih  = (const float*)d_in[2];
  const float* Whh  = (const float*)d_in[3];
  const float* bhh  = (const float*)d_in[4];
  const float* Wout = (const float*)d_in[5];
  const float* bout = (const float*)d_in[6];
  float* out = (float*)d_out;

  char* ws = (char*)d_ws;
  float* xp          = (float*)(ws);                                // [512][8][2048] fp32, 32 MiB
  unsigned short* hs = (unsigned short*)(ws + (size_t)(32 << 20));  // [8][512][2048] bf16, 16 MiB

  // Phase 0: sentinel-fill hs (16 MiB / 16 B = 1,048,576 uint4)
  sentinel_kernel<<<dim3(4096), 256, 0, stream>>>((u32x4*)hs);
  // Phase 1: xp = x @ W_ih^T + b_ih + b_hh
  gemm_kernel<0><<<dim3(64, 32), 256, 0, stream>>>(x, Wih, bih, bhh, xp, IN_K, HID);
  // Phase 2: barrier-free sequential scan
  scan_kernel<<<dim3(NWG), 256, 0, stream>>>(Whh, xp, hs);
  // Phase 3: out = hs @ W_out^T + b_out
  gemm_kernel<1><<<dim3(64, 2), 256, 0, stream>>>(hs, Wout, bout, nullptr, out, HID, OUTN);
}